// Round 1
// baseline (389.519 us; speedup 1.0000x reference)
//
#include <hip/hip_runtime.h>
#include <hip/hip_bf16.h>
#include <math.h>

#define L 2048
#define NH 10
#define DP 32
#define D30 30

typedef __attribute__((ext_vector_type(8))) short bf16x8;
typedef __attribute__((ext_vector_type(4))) float f32x4;

__device__ inline short f2bf(float f) {
    union { float f; unsigned u; } v; v.f = f;
    unsigned r = (v.u + 0x7FFF + ((v.u >> 16) & 1)) >> 16;
    return (short)r;
}

// ---------------- Projection kernel ----------------
// og0: Wq,x -> K part0 + V part0 (+Vt); og1: Wk,ax[al=0] -> K part1;
// og2: Wk,ax[al=1] -> K part2; og3: Wv,ax[al=0] -> V part1 (+Vt);
// og4: Wv,ax[al=1] -> V part2 (+Vt).  d = 3*(c%10) + part, h = c/10.
__global__ __launch_bounds__(256) void proj_kernel(
    const float* __restrict__ x, const float* __restrict__ ax,
    const float* __restrict__ wq, const float* __restrict__ bq,
    const float* __restrict__ wk, const float* __restrict__ bk,
    const float* __restrict__ wv, const float* __restrict__ bv,
    short* __restrict__ Kbuf, short* __restrict__ Vbuf, short* __restrict__ Vtbuf)
{
    __shared__ float Xt[128 * 68];   // [l_local 0..127][ci_local 0..63], stride 68
    __shared__ float Wl[128 * 68];   // [c 0..127][ci_local 0..63], stride 68
    const int t  = threadIdx.x;
    const int bx = blockIdx.x;       // l tile (128)
    const int og = blockIdx.y;       // 0..4
    const int b  = blockIdx.z;
    const int l0 = bx * 128;

    const float* W; const float* bias;
    if (og == 0)      { W = wq; bias = bq; }
    else if (og <= 2) { W = wk; bias = bk; }
    else              { W = wv; bias = bv; }
    const int al = (og - 1) & 1;

    const int cg = t >> 4;   // 0..15
    const int lg = t & 15;   // 0..15

    float acc[8][8];
    #pragma unroll
    for (int j = 0; j < 8; j++)
        #pragma unroll
        for (int i = 0; i < 8; i++) acc[j][i] = 0.f;

    for (int cc = 0; cc < 4; cc++) {
        const int c0 = cc * 64;
        __syncthreads();
        // stage W chunk (rows >=100 zeroed)
        for (int k = t; k < 128 * 64; k += 256) {
            int row = k >> 6, col = k & 63;
            Wl[row * 68 + col] = (row < 100) ? W[row * 256 + c0 + col] : 0.f;
        }
        // stage X^T
        {
            int r = t >> 2;          // ci local 0..63
            int q = t & 3;
            const float* src;
            if (og == 0) src = x  + ((size_t)(b * 256 + c0 + r)) * L + l0;
            else         src = ax + (((size_t)(b * 256 + c0 + r)) * 2 + al) * L + l0;
            #pragma unroll
            for (int jj = 0; jj < 8; jj++) {
                int col4 = q * 8 + jj;
                float4 vv = *(const float4*)(src + col4 * 4);
                Xt[(col4 * 4 + 0) * 68 + r] = vv.x;
                Xt[(col4 * 4 + 1) * 68 + r] = vv.y;
                Xt[(col4 * 4 + 2) * 68 + r] = vv.z;
                Xt[(col4 * 4 + 3) * 68 + r] = vv.w;
            }
        }
        __syncthreads();
        #pragma unroll 4
        for (int ci4 = 0; ci4 < 16; ci4++) {
            float4 w4[8], x4[8];
            #pragma unroll
            for (int j = 0; j < 8; j++)
                w4[j] = *(const float4*)(&Wl[(cg + 16 * j) * 68 + ci4 * 4]);
            #pragma unroll
            for (int i = 0; i < 8; i++)
                x4[i] = *(const float4*)(&Xt[(lg + 16 * i) * 68 + ci4 * 4]);
            #pragma unroll
            for (int j = 0; j < 8; j++)
                #pragma unroll
                for (int i = 0; i < 8; i++) {
                    acc[j][i] += w4[j].x * x4[i].x;
                    acc[j][i] += w4[j].y * x4[i].y;
                    acc[j][i] += w4[j].z * x4[i].z;
                    acc[j][i] += w4[j].w * x4[i].w;
                }
        }
    }

    const int part = (og == 0) ? 0 : ((og == 1 || og == 3) ? 1 : 2);
    #pragma unroll
    for (int j = 0; j < 8; j++) {
        int c = cg + 16 * j;
        if (c >= 100) continue;
        float bc = bias[c];
        int h = c / 10, i10 = c % 10;
        int dd = 3 * i10 + part;
        size_t rowbase = ((size_t)(b * NH + h)) * L;
        size_t tbase   = ((size_t)(b * NH + h) * DP + dd) * L;
        #pragma unroll
        for (int i = 0; i < 8; i++) {
            int l = l0 + lg + 16 * i;
            short bv16 = f2bf(acc[j][i] + bc);
            if (og == 0) {
                Kbuf[(rowbase + l) * DP + dd] = bv16;
                Vbuf[(rowbase + l) * DP + dd] = bv16;
                Vtbuf[tbase + l] = bv16;
            } else if (og <= 2) {
                Kbuf[(rowbase + l) * DP + dd] = bv16;
            } else {
                Vbuf[(rowbase + l) * DP + dd] = bv16;
                Vtbuf[tbase + l] = bv16;
            }
        }
    }
}

// ---------------- Flash attention kernel ----------------
// block = (b, h, 64 query rows); 4 waves, each owns 16 rows; no __syncthreads.
__global__ __launch_bounds__(256) void attn_kernel(
    const short* __restrict__ Kbuf, const short* __restrict__ Vbuf,
    const short* __restrict__ Vtbuf, const float* __restrict__ edge,
    float* __restrict__ attbuf)
{
    __shared__ short Pl[4 * 16 * 72];   // per-wave private 16x64 P tile, stride 72
    const int t    = threadIdx.x;
    const int w    = t >> 6;
    const int lane = t & 63;
    const int quad = lane >> 4;
    const int l15  = lane & 15;
    const int l0   = blockIdx.x * 64;
    const int h    = blockIdx.y;
    const int b    = blockIdx.z;
    const size_t bh = (size_t)(b * NH + h);

    // K A-fragment: constant across the whole m loop
    const int lrow = l0 + w * 16 + l15;
    bf16x8 kfrag = *(const bf16x8*)(Kbuf + (bh * L + lrow) * DP + quad * 8);

    const float scale = 0.31622776601683794f;   // 1/sqrt(10)
    float mrun[4], lsum[4];
    f32x4 O0 = {0,0,0,0}, O1 = {0,0,0,0};
    #pragma unroll
    for (int r = 0; r < 4; r++) { mrun[r] = -INFINITY; lsum[r] = 0.f; }

    short* myP = Pl + w * (16 * 72);
    const int myrow_l = l0 + w * 16 + quad * 4;   // + r
    const float* edge_base = edge + (size_t)b * L * L;

    for (int mt = 0; mt < 32; mt++) {
        const int m0 = mt * 64;
        // QK^T: S[16 x 64] via 4 MFMAs (B-frags direct from global Vbuf)
        f32x4 S[4];
        #pragma unroll
        for (int nb = 0; nb < 4; nb++) {
            bf16x8 vfrag = *(const bf16x8*)(Vbuf + (bh * L + m0 + nb * 16 + l15) * DP + quad * 8);
            f32x4 z = {0,0,0,0};
            S[nb] = __builtin_amdgcn_mfma_f32_16x16x32_bf16(kfrag, vfrag, z, 0, 0, 0);
        }
        // edge-modulated scores + tile row max
        float p[4][4], tmax[4];
        #pragma unroll
        for (int r = 0; r < 4; r++) tmax[r] = -INFINITY;
        #pragma unroll
        for (int nb = 0; nb < 4; nb++)
            #pragma unroll
            for (int r = 0; r < 4; r++) {
                float e  = edge_base[(size_t)(myrow_l + r) * L + (m0 + nb * 16 + l15)];
                float sv = S[nb][r] * e * scale;
                p[nb][r] = sv;
                tmax[r]  = fmaxf(tmax[r], sv);
            }
        #pragma unroll
        for (int r = 0; r < 4; r++) {
            float v = tmax[r];
            v = fmaxf(v, __shfl_xor(v, 1));
            v = fmaxf(v, __shfl_xor(v, 2));
            v = fmaxf(v, __shfl_xor(v, 4));
            v = fmaxf(v, __shfl_xor(v, 8));
            float mnew = fmaxf(mrun[r], v);
            float s = 0.f;
            #pragma unroll
            for (int nb = 0; nb < 4; nb++) {
                float pe = __expf(p[nb][r] - mnew);
                p[nb][r] = pe;
                s += pe;
            }
            s += __shfl_xor(s, 1); s += __shfl_xor(s, 2);
            s += __shfl_xor(s, 4); s += __shfl_xor(s, 8);
            float alpha = __expf(mrun[r] - mnew);
            lsum[r] = lsum[r] * alpha + s;
            mrun[r] = mnew;
            O0[r] *= alpha; O1[r] *= alpha;
        }
        // P (C-layout) -> LDS -> A-layout
        #pragma unroll
        for (int nb = 0; nb < 4; nb++)
            #pragma unroll
            for (int r = 0; r < 4; r++)
                myP[(quad * 4 + r) * 72 + nb * 16 + l15] = f2bf(p[nb][r]);
        #pragma unroll
        for (int ks = 0; ks < 2; ks++) {
            bf16x8 afrag = *(const bf16x8*)(myP + l15 * 72 + ks * 32 + quad * 8);
            bf16x8 b0 = *(const bf16x8*)(Vtbuf + (bh * DP + l15)      * L + m0 + ks * 32 + quad * 8);
            bf16x8 b1 = *(const bf16x8*)(Vtbuf + (bh * DP + 16 + l15) * L + m0 + ks * 32 + quad * 8);
            O0 = __builtin_amdgcn_mfma_f32_16x16x32_bf16(afrag, b0, O0, 0, 0, 0);
            O1 = __builtin_amdgcn_mfma_f32_16x16x32_bf16(afrag, b1, O1, 0, 0, 0);
        }
    }
    // epilogue: normalize and store at the torch-view flat index h*L*30 + l*30 + d
    float* ab = attbuf + (size_t)b * (NH * L * D30);
    #pragma unroll
    for (int r = 0; r < 4; r++) {
        int l = myrow_l + r;
        float inv = 1.f / lsum[r];
        size_t base = (size_t)h * (L * D30) + (size_t)l * D30;
        ab[base + l15] = O0[r] * inv;
        int d1 = 16 + l15;
        if (d1 < D30) ab[base + d1] = O1[r] * inv;
    }
}

// ---------------- Output projection ----------------
// out[b,o,m] = bo[o] + sum_c wo[o,c] * attview[b][c][m]  (attview = attbuf as [300][2048])
__global__ __launch_bounds__(256) void out_kernel(
    const float* __restrict__ attbuf, const float* __restrict__ wo,
    const float* __restrict__ bo, float* __restrict__ out)
{
    const int t  = threadIdx.x;
    const int og = t >> 3;            // o = og*8 .. +7
    const int mg = t & 7;             // m = m0 + mg*4 .. +3
    const int m0 = blockIdx.x * 32;
    const int b  = blockIdx.y;
    const float* ab = attbuf + (size_t)b * (NH * L * D30);

    float acc[8][4];
    #pragma unroll
    for (int j = 0; j < 8; j++)
        #pragma unroll
        for (int i = 0; i < 4; i++) acc[j][i] = 0.f;

    for (int c = 0; c < 300; c += 4) {
        float4 a[4];
        #pragma unroll
        for (int cc = 0; cc < 4; cc++)
            a[cc] = *(const float4*)(ab + (size_t)(c + cc) * L + m0 + mg * 4);
        #pragma unroll
        for (int j = 0; j < 8; j++) {
            int o = og * 8 + j;
            float4 w4 = *(const float4*)(wo + o * 300 + c);
            acc[j][0] += w4.x * a[0].x + w4.y * a[1].x + w4.z * a[2].x + w4.w * a[3].x;
            acc[j][1] += w4.x * a[0].y + w4.y * a[1].y + w4.z * a[2].y + w4.w * a[3].y;
            acc[j][2] += w4.x * a[0].z + w4.y * a[1].z + w4.z * a[2].z + w4.w * a[3].z;
            acc[j][3] += w4.x * a[0].w + w4.y * a[1].w + w4.z * a[2].w + w4.w * a[3].w;
        }
    }
    float* ob = out + (size_t)b * 256 * L;
    #pragma unroll
    for (int j = 0; j < 8; j++) {
        int o = og * 8 + j;
        float bias = bo[o];
        float4 r;
        r.x = acc[j][0] + bias; r.y = acc[j][1] + bias;
        r.z = acc[j][2] + bias; r.w = acc[j][3] + bias;
        *(float4*)(ob + (size_t)o * L + m0 + mg * 4) = r;
    }
}

extern "C" void kernel_launch(void* const* d_in, const int* in_sizes, int n_in,
                              void* d_out, int out_size, void* d_ws, size_t ws_size,
                              hipStream_t stream) {
    const float* x    = (const float*)d_in[0];
    const float* ax   = (const float*)d_in[1];
    const float* edge = (const float*)d_in[2];
    const float* wq   = (const float*)d_in[3];
    const float* bq   = (const float*)d_in[4];
    const float* wk   = (const float*)d_in[5];
    const float* bk   = (const float*)d_in[6];
    const float* wv   = (const float*)d_in[7];
    const float* bv   = (const float*)d_in[8];
    const float* wo   = (const float*)d_in[9];
    const float* bo   = (const float*)d_in[10];
    float* out = (float*)d_out;

    // workspace layout
    const size_t KB = (size_t)4 * NH * L * DP * 2;   // 5,242,880 B (bf16)
    char* ws = (char*)d_ws;
    short* Kbuf   = (short*)ws;
    short* Vbuf   = (short*)(ws + KB);
    short* Vtbuf  = (short*)(ws + 2 * KB);
    float* attbuf = (float*)(ws + 3 * KB);           // 9,830,400 B (fp32)
    if (ws_size < 3 * KB + (size_t)4 * NH * L * D30 * 4) return;  // fail loudly

    // zero K/V/Vt (covers the d=30,31 pad columns)
    hipMemsetAsync(ws, 0, 3 * KB, stream);

    proj_kernel<<<dim3(16, 5, 4), 256, 0, stream>>>(x, ax, wq, bq, wk, bk, wv, bv,
                                                    Kbuf, Vbuf, Vtbuf);
    attn_kernel<<<dim3(32, NH, 4), 256, 0, stream>>>(Kbuf, Vbuf, Vtbuf, edge, attbuf);
    out_kernel<<<dim3(64, 4, 1), 256, 0, stream>>>(attbuf, wo, bo, out);
}